// Round 1
// baseline (1976.299 us; speedup 1.0000x reference)
//
#include <hip/hip_runtime.h>
#include <hip/hip_fp16.h>

#define N_NODES 50000
#define N_EDGES 800000
#define IN_DIM  128
#define EDGE_DIM 16
#define HID     64
#define HID2    128
#define OUT_DIM 8
#define N_LAYERS 4

// ---------------------------------------------------------------------------
// h0 = x @ node_W + node_b      [N,128]@[128,64]
// block = 256 thr = 4 nodes x 64 ch; W column (128) in VGPRs, x staged in LDS.
// ---------------------------------------------------------------------------
__global__ __launch_bounds__(256, 2) void node_proj_kernel(
    const float* __restrict__ x, const float* __restrict__ W,
    const float* __restrict__ b, float* __restrict__ h)
{
    __shared__ float xs[4][IN_DIM];
    const int c = threadIdx.x & 63;
    const int local_n = threadIdx.x >> 6;
    float w[IN_DIM];
#pragma unroll
    for (int k = 0; k < IN_DIM; ++k) w[k] = W[k * HID + c];
    const float bias = b[c];

    for (int base = blockIdx.x * 4; base < N_NODES; base += gridDim.x * 4) {
        __syncthreads();
#pragma unroll
        for (int i = 0; i < 2; ++i) {
            int idx = threadIdx.x + i * 256;          // 0..511
            int nn = idx >> 7, kk = idx & 127;
            xs[nn][kk] = x[(base + nn) * IN_DIM + kk]; // 50000 % 4 == 0
        }
        __syncthreads();
        const int n = base + local_n;
        float acc = bias;
#pragma unroll
        for (int k4 = 0; k4 < IN_DIM / 4; ++k4) {
            float4 xv = ((const float4*)xs[local_n])[k4];
            acc = fmaf(xv.x, w[k4 * 4 + 0], acc);
            acc = fmaf(xv.y, w[k4 * 4 + 1], acc);
            acc = fmaf(xv.z, w[k4 * 4 + 2], acc);
            acc = fmaf(xv.w, w[k4 * 4 + 3], acc);
        }
        h[n * HID + c] = acc;
    }
}

// ---------------------------------------------------------------------------
// eah = fp16( edge_attr @ edge_W + edge_b )   [E,16]@[16,64] -> half [E,64]
// wave per edge; lane = channel; edge_W column (16) in VGPRs.
// ---------------------------------------------------------------------------
__global__ __launch_bounds__(256, 4) void edge_emb_kernel(
    const float* __restrict__ ea, const float* __restrict__ W,
    const float* __restrict__ b, __half* __restrict__ eah)
{
    const int lane = threadIdx.x & 63;
    const int wave = (blockIdx.x * 256 + threadIdx.x) >> 6;
    const int nwaves = gridDim.x * 4;
    float w[EDGE_DIM];
#pragma unroll
    for (int k = 0; k < EDGE_DIM; ++k) w[k] = W[k * HID + lane];
    const float bias = b[lane];

    for (int e = wave; e < N_EDGES; e += nwaves) {
        const float4* ap = (const float4*)(ea + (long)e * EDGE_DIM);
        float acc = bias;
#pragma unroll
        for (int k4 = 0; k4 < EDGE_DIM / 4; ++k4) {
            float4 av = ap[k4];                       // broadcast (same addr)
            acc = fmaf(av.x, w[k4 * 4 + 0], acc);
            acc = fmaf(av.y, w[k4 * 4 + 1], acc);
            acc = fmaf(av.z, w[k4 * 4 + 2], acc);
            acc = fmaf(av.w, w[k4 * 4 + 3], acc);
        }
        eah[(long)e * HID + lane] = __float2half(acc);
    }
}

// ---------------------------------------------------------------------------
// Edge sweep: msg = relu(z[src]+ea)+eps ; e = exp(msg*t) ;
//             s[dst] += e ; p[dst] += msg*e      (unstabilized softmax — safe,
//             logits bounded; identical math to segment_softmax)
// ---------------------------------------------------------------------------
__global__ __launch_bounds__(256, 4) void edge_pass_kernel(
    const float* __restrict__ zin, const __half* __restrict__ eah,
    const int* __restrict__ srcs, const int* __restrict__ dsts,
    const float* __restrict__ conv_t, int layer,
    float* __restrict__ p, float* __restrict__ s)
{
    const int lane = threadIdx.x & 63;
    const int wave = (blockIdx.x * 256 + threadIdx.x) >> 6;
    const int nwaves = gridDim.x * 4;
    const float t = conv_t[layer];

    for (int e = wave; e < N_EDGES; e += nwaves) {
        const int src = srcs[e];
        const int dst = dsts[e];
        float z = zin[src * HID + lane];
        float ea = __half2float(eah[(long)e * HID + lane]);
        float m = z + ea;
        m = (m > 0.f ? m : 0.f) + 1e-7f;
        float el = __expf(m * t);
        unsafeAtomicAdd(&s[dst * HID + lane], el);
        unsafeAtomicAdd(&p[dst * HID + lane], m * el);
    }
}

// ---------------------------------------------------------------------------
// mm1: hin = p/(s+1e-16) + zin ; u = hin@W1 + b1 ; v = relu(LN128(u)*g1+be1)
// block = 256 thr = 2 nodes x 128 cols; W1 column (64) in VGPRs.
// ---------------------------------------------------------------------------
__global__ __launch_bounds__(256, 2) void node_mm1_kernel(
    const float* __restrict__ p, const float* __restrict__ s,
    const float* __restrict__ zin,
    const float* __restrict__ W1, const float* __restrict__ b1,
    const float* __restrict__ g1, const float* __restrict__ be1,
    float* __restrict__ v)
{
    __shared__ float hs[2][HID];
    __shared__ float red[2][2][2];
    const int j = threadIdx.x & 127;
    const int local_n = threadIdx.x >> 7;
    const int wavehalf = (threadIdx.x >> 6) & 1;
    float w[HID];
#pragma unroll
    for (int k = 0; k < HID; ++k) w[k] = W1[k * HID2 + j];
    const float bias = b1[j];
    const float g = g1[j];
    const float be = be1[j];

    for (int base = blockIdx.x * 2; base < N_NODES; base += gridDim.x * 2) {
        __syncthreads();
        if (threadIdx.x < 128) {                       // stage hin (2 x 64)
            int nn = threadIdx.x >> 6, c = threadIdx.x & 63;
            int idx = (base + nn) * HID + c;           // 50000 % 2 == 0
            hs[nn][c] = p[idx] / (s[idx] + 1e-16f) + zin[idx];
        }
        __syncthreads();
        const int n = base + local_n;
        float u = bias;
#pragma unroll
        for (int k4 = 0; k4 < HID / 4; ++k4) {
            float4 hv = ((const float4*)hs[local_n])[k4];
            u = fmaf(hv.x, w[k4 * 4 + 0], u);
            u = fmaf(hv.y, w[k4 * 4 + 1], u);
            u = fmaf(hv.z, w[k4 * 4 + 2], u);
            u = fmaf(hv.w, w[k4 * 4 + 3], u);
        }
        // LayerNorm over 128 (2 waves per node)
        float ps_ = u;
#pragma unroll
        for (int o = 1; o < 64; o <<= 1) ps_ += __shfl_xor(ps_, o, 64);
        if ((threadIdx.x & 63) == 0) red[local_n][0][wavehalf] = ps_;
        __syncthreads();
        const float mu = (red[local_n][0][0] + red[local_n][0][1]) * (1.f / 128.f);
        const float d = u - mu;
        float q = d * d;
#pragma unroll
        for (int o = 1; o < 64; o <<= 1) q += __shfl_xor(q, o, 64);
        if ((threadIdx.x & 63) == 0) red[local_n][1][wavehalf] = q;
        __syncthreads();
        const float var = (red[local_n][1][0] + red[local_n][1][1]) * (1.f / 128.f);
        const float y = d * rsqrtf(var + 1e-5f) * g + be;
        v[n * HID2 + j] = y > 0.f ? y : 0.f;
    }
}

// ---------------------------------------------------------------------------
// mm2: out2 = v@W2 + b2 ; h = (residual? h:0) + out2 ;
//      z = relu(LN64(h)*gz+bz)   (gz/bz = next layer's ln params, or ln[0]
//      after the last layer -> z becomes the final pre-lin activation)
// block = 256 thr = 4 nodes x 64 ch (wave == node); W2 column (128) in VGPRs.
// ---------------------------------------------------------------------------
__global__ __launch_bounds__(256, 2) void node_mm2_kernel(
    const float* __restrict__ v,
    const float* __restrict__ W2, const float* __restrict__ b2,
    const float* __restrict__ lng, const float* __restrict__ lnb,
    float* __restrict__ h, float* __restrict__ z, int residual)
{
    __shared__ float vs[4][HID2];
    const int c = threadIdx.x & 63;
    const int local_n = threadIdx.x >> 6;
    float w[HID2];
#pragma unroll
    for (int k = 0; k < HID2; ++k) w[k] = W2[k * HID + c];
    const float bias = b2[c];
    const float g = lng[c];
    const float be = lnb[c];

    for (int base = blockIdx.x * 4; base < N_NODES; base += gridDim.x * 4) {
        __syncthreads();
#pragma unroll
        for (int i = 0; i < 2; ++i) {
            int idx = threadIdx.x + i * 256;           // 0..511
            int nn = idx >> 7, kk = idx & 127;
            vs[nn][kk] = v[(base + nn) * HID2 + kk];   // 50000 % 4 == 0
        }
        __syncthreads();
        const int n = base + local_n;
        float acc = bias;
#pragma unroll
        for (int k4 = 0; k4 < HID2 / 4; ++k4) {
            float4 vv = ((const float4*)vs[local_n])[k4];
            acc = fmaf(vv.x, w[k4 * 4 + 0], acc);
            acc = fmaf(vv.y, w[k4 * 4 + 1], acc);
            acc = fmaf(vv.z, w[k4 * 4 + 2], acc);
            acc = fmaf(vv.w, w[k4 * 4 + 3], acc);
        }
        const float hn = residual ? (h[n * HID + c] + acc) : acc;
        h[n * HID + c] = hn;
        // LayerNorm over 64 within the wave
        float ps_ = hn;
#pragma unroll
        for (int o = 1; o < 64; o <<= 1) ps_ += __shfl_xor(ps_, o, 64);
        const float mu = ps_ * (1.f / 64.f);
        const float d = hn - mu;
        float q = d * d;
#pragma unroll
        for (int o = 1; o < 64; o <<= 1) q += __shfl_xor(q, o, 64);
        const float var = q * (1.f / 64.f);
        const float y = d * rsqrtf(var + 1e-5f) * g + be;
        z[n * HID + c] = y > 0.f ? y : 0.f;
    }
}

// ---------------------------------------------------------------------------
// out = z @ lin_W + lin_b      [N,64]@[64,8]
// ---------------------------------------------------------------------------
__global__ __launch_bounds__(256, 4) void final_kernel(
    const float* __restrict__ z, const float* __restrict__ Wl,
    const float* __restrict__ bl, float* __restrict__ out)
{
    __shared__ float wl[HID * OUT_DIM];
    for (int i = threadIdx.x; i < HID * OUT_DIM; i += 256) wl[i] = Wl[i];
    __syncthreads();
    const int total = N_NODES * OUT_DIM;
    for (int idx = blockIdx.x * 256 + threadIdx.x; idx < total;
         idx += gridDim.x * 256) {
        const int n = idx >> 3, o = idx & 7;
        const float4* zp4 = (const float4*)(z + n * HID);
        float acc = bl[o];
#pragma unroll
        for (int k4 = 0; k4 < HID / 4; ++k4) {
            float4 zv = zp4[k4];
            acc = fmaf(zv.x, wl[(k4 * 4 + 0) * OUT_DIM + o], acc);
            acc = fmaf(zv.y, wl[(k4 * 4 + 1) * OUT_DIM + o], acc);
            acc = fmaf(zv.z, wl[(k4 * 4 + 2) * OUT_DIM + o], acc);
            acc = fmaf(zv.w, wl[(k4 * 4 + 3) * OUT_DIM + o], acc);
        }
        out[idx] = acc;
    }
}

// ---------------------------------------------------------------------------
extern "C" void kernel_launch(void* const* d_in, const int* in_sizes, int n_in,
                              void* d_out, int out_size, void* d_ws, size_t ws_size,
                              hipStream_t stream)
{
    const float* x         = (const float*)d_in[0];
    const float* edge_attr = (const float*)d_in[1];
    const float* node_W    = (const float*)d_in[2];
    const float* node_b    = (const float*)d_in[3];
    const float* edge_W    = (const float*)d_in[4];
    const float* edge_b    = (const float*)d_in[5];
    const float* conv_t    = (const float*)d_in[6];
    const float* conv_W1   = (const float*)d_in[7];
    const float* conv_b1   = (const float*)d_in[8];
    const float* conv_g1   = (const float*)d_in[9];
    const float* conv_be1  = (const float*)d_in[10];
    const float* conv_W2   = (const float*)d_in[11];
    const float* conv_b2   = (const float*)d_in[12];
    const float* ln_g      = (const float*)d_in[13];
    const float* ln_b      = (const float*)d_in[14];
    const float* lin_W     = (const float*)d_in[15];
    const float* lin_b     = (const float*)d_in[16];
    const int*   edge_index= (const int*)d_in[17];
    const int*   srcs = edge_index;
    const int*   dsts = edge_index + N_EDGES;
    float* out = (float*)d_out;

    // workspace layout (needs ~179.2 MB)
    float* h  = (float*)d_ws;                  // N*64
    float* z  = h  + N_NODES * HID;            // N*64
    float* p  = z  + N_NODES * HID;            // N*64
    float* s  = p  + N_NODES * HID;            // N*64  (p,s contiguous)
    float* v  = s  + N_NODES * HID;            // N*128
    __half* eah = (__half*)(v + N_NODES * HID2); // E*64 half

    node_proj_kernel<<<2048, 256, 0, stream>>>(x, node_W, node_b, h);
    edge_emb_kernel<<<4096, 256, 0, stream>>>(edge_attr, edge_W, edge_b, eah);

    for (int layer = 0; layer < N_LAYERS; ++layer) {
        hipMemsetAsync(p, 0, (size_t)N_NODES * HID2 * sizeof(float), stream);
        const float* zin = (layer == 0) ? h : z;
        edge_pass_kernel<<<4096, 256, 0, stream>>>(zin, eah, srcs, dsts,
                                                   conv_t, layer, p, s);
        node_mm1_kernel<<<2048, 256, 0, stream>>>(
            p, s, zin,
            conv_W1 + (size_t)layer * HID * HID2, conv_b1 + layer * HID2,
            conv_g1 + layer * HID2, conv_be1 + layer * HID2, v);
        const float* gz = (layer < N_LAYERS - 1) ? (ln_g + (layer + 1) * HID) : ln_g;
        const float* bz = (layer < N_LAYERS - 1) ? (ln_b + (layer + 1) * HID) : ln_b;
        node_mm2_kernel<<<2048, 256, 0, stream>>>(
            v, conv_W2 + (size_t)layer * HID2 * HID, conv_b2 + layer * HID,
            gz, bz, h, z, layer > 0 ? 1 : 0);
    }
    final_kernel<<<1024, 256, 0, stream>>>(z, lin_W, lin_b, out);
}

// Round 2
// 1045.605 us; speedup vs baseline: 1.8901x; 1.8901x over previous
//
#include <hip/hip_runtime.h>
#include <hip/hip_fp16.h>

#define N_NODES 50000
#define N_EDGES 800000
#define IN_DIM  128
#define EDGE_DIM 16
#define HID     64
#define HID2    128
#define OUT_DIM 8
#define N_LAYERS 4

// ---------------------------------------------------------------------------
// Counting sort of edges by dst: histogram -> exclusive scan -> scatter.
// ---------------------------------------------------------------------------
__global__ __launch_bounds__(256, 4) void hist_kernel(
    const int* __restrict__ dsts, int* __restrict__ deg)
{
    for (int e = blockIdx.x * 256 + threadIdx.x; e < N_EDGES;
         e += gridDim.x * 256)
        atomicAdd(&deg[dsts[e]], 1);
}

// single block, 1024 threads; exclusive scan of deg[0..N) -> offsets[0..N]
__global__ __launch_bounds__(1024, 1) void scan_kernel(
    const int* __restrict__ deg, int* __restrict__ offsets)
{
    __shared__ int part[1024];
    const int t = threadIdx.x;
    const int CHUNK = (N_NODES + 1023) / 1024;           // 49
    const int lo = t * CHUNK;
    const int hi = min(lo + CHUNK, N_NODES);
    int sum = 0;
    for (int i = lo; i < hi; ++i) sum += deg[i];
    part[t] = sum;
    __syncthreads();
    for (int off = 1; off < 1024; off <<= 1) {           // Hillis-Steele incl.
        int v_ = (t >= off) ? part[t - off] : 0;
        __syncthreads();
        part[t] += v_;
        __syncthreads();
    }
    int run = (t > 0) ? part[t - 1] : 0;                 // exclusive base
    for (int i = lo; i < hi; ++i) { offsets[i] = run; run += deg[i]; }
    if (t == 1023) offsets[N_NODES] = part[1023];        // total
}

// pos = cursor[dst]++ ; sid[pos] = e ; ssrc[pos] = src[e]
__global__ __launch_bounds__(256, 4) void scatter_kernel(
    const int* __restrict__ srcs, const int* __restrict__ dsts,
    int* __restrict__ cursor, int* __restrict__ sid, int* __restrict__ ssrc)
{
    for (int e = blockIdx.x * 256 + threadIdx.x; e < N_EDGES;
         e += gridDim.x * 256) {
        const int d = dsts[e];
        const int pos = atomicAdd(&cursor[d], 1);
        sid[pos] = e;
        ssrc[pos] = srcs[e];
    }
}

// ---------------------------------------------------------------------------
// h0 = x @ node_W + node_b      [N,128]@[128,64]
// ---------------------------------------------------------------------------
__global__ __launch_bounds__(256, 2) void node_proj_kernel(
    const float* __restrict__ x, const float* __restrict__ W,
    const float* __restrict__ b, float* __restrict__ h)
{
    __shared__ float xs[4][IN_DIM];
    const int c = threadIdx.x & 63;
    const int local_n = threadIdx.x >> 6;
    float w[IN_DIM];
#pragma unroll
    for (int k = 0; k < IN_DIM; ++k) w[k] = W[k * HID + c];
    const float bias = b[c];

    for (int base = blockIdx.x * 4; base < N_NODES; base += gridDim.x * 4) {
        __syncthreads();
#pragma unroll
        for (int i = 0; i < 2; ++i) {
            int idx = threadIdx.x + i * 256;
            int nn = idx >> 7, kk = idx & 127;
            xs[nn][kk] = x[(base + nn) * IN_DIM + kk];
        }
        __syncthreads();
        const int n = base + local_n;
        float acc = bias;
#pragma unroll
        for (int k4 = 0; k4 < IN_DIM / 4; ++k4) {
            float4 xv = ((const float4*)xs[local_n])[k4];
            acc = fmaf(xv.x, w[k4 * 4 + 0], acc);
            acc = fmaf(xv.y, w[k4 * 4 + 1], acc);
            acc = fmaf(xv.z, w[k4 * 4 + 2], acc);
            acc = fmaf(xv.w, w[k4 * 4 + 3], acc);
        }
        h[n * HID + c] = acc;
    }
}

// ---------------------------------------------------------------------------
// eah[pos] = fp16( edge_attr[sid[pos]] @ edge_W + edge_b )  -- written in
// dst-sorted order so the per-layer sweep reads it fully streaming.
// ---------------------------------------------------------------------------
__global__ __launch_bounds__(256, 4) void edge_emb_kernel(
    const float* __restrict__ ea, const float* __restrict__ W,
    const float* __restrict__ b, const int* __restrict__ sid,
    __half* __restrict__ eah)
{
    const int lane = threadIdx.x & 63;
    const int wave = (blockIdx.x * 256 + threadIdx.x) >> 6;
    const int nwaves = gridDim.x * 4;
    float w[EDGE_DIM];
#pragma unroll
    for (int k = 0; k < EDGE_DIM; ++k) w[k] = W[k * HID + lane];
    const float bias = b[lane];

    for (int pos = wave; pos < N_EDGES; pos += nwaves) {
        const int e = sid[pos];
        const float4* ap = (const float4*)(ea + (long)e * EDGE_DIM);
        float acc = bias;
#pragma unroll
        for (int k4 = 0; k4 < EDGE_DIM / 4; ++k4) {
            float4 av = ap[k4];                      // wave-uniform broadcast
            acc = fmaf(av.x, w[k4 * 4 + 0], acc);
            acc = fmaf(av.y, w[k4 * 4 + 1], acc);
            acc = fmaf(av.z, w[k4 * 4 + 2], acc);
            acc = fmaf(av.w, w[k4 * 4 + 3], acc);
        }
        eah[(long)pos * HID + lane] = __float2half(acc);
    }
}

// ---------------------------------------------------------------------------
// Segmented softmax-aggregate, no atomics: one wave per node.
// agg[n] = sum(m*e)/ (sum(e)+1e-16), m = relu(z[src]+ea)+eps, e = exp(m*t)
// ---------------------------------------------------------------------------
__global__ __launch_bounds__(256, 4) void edge_agg_kernel(
    const float* __restrict__ zin, const __half* __restrict__ eah,
    const int* __restrict__ ssrc, const int* __restrict__ offsets,
    const float* __restrict__ conv_t, int layer, float* __restrict__ agg)
{
    const int lane = threadIdx.x & 63;
    const int wave = (blockIdx.x * 256 + threadIdx.x) >> 6;
    const int nwaves = gridDim.x * 4;
    const float t = conv_t[layer];

    for (int n = wave; n < N_NODES; n += nwaves) {
        const int s0 = offsets[n];
        const int s1 = offsets[n + 1];
        float S = 0.f, P = 0.f;
        int i = s0;
        for (; i + 1 < s1; i += 2) {                 // 2x unroll for MLP
            const int a = ssrc[i];
            const int b = ssrc[i + 1];
            float za = zin[a * HID + lane];
            float zb = zin[b * HID + lane];
            float ea = __half2float(eah[(long)i * HID + lane]);
            float eb = __half2float(eah[(long)(i + 1) * HID + lane]);
            float ma = fmaxf(za + ea, 0.f) + 1e-7f;
            float mb = fmaxf(zb + eb, 0.f) + 1e-7f;
            float ela = __expf(ma * t);
            float elb = __expf(mb * t);
            S += ela + elb;
            P = fmaf(ma, ela, fmaf(mb, elb, P));
        }
        if (i < s1) {
            const int a = ssrc[i];
            float za = zin[a * HID + lane];
            float ea = __half2float(eah[(long)i * HID + lane]);
            float ma = fmaxf(za + ea, 0.f) + 1e-7f;
            float ela = __expf(ma * t);
            S += ela;
            P = fmaf(ma, ela, P);
        }
        agg[n * HID + lane] = P / (S + 1e-16f);
    }
}

// ---------------------------------------------------------------------------
// mm1: hin = agg + zin ; u = hin@W1 + b1 ; v = relu(LN128(u)*g1+be1)
// ---------------------------------------------------------------------------
__global__ __launch_bounds__(256, 2) void node_mm1_kernel(
    const float* __restrict__ agg, const float* __restrict__ zin,
    const float* __restrict__ W1, const float* __restrict__ b1,
    const float* __restrict__ g1, const float* __restrict__ be1,
    float* __restrict__ v)
{
    __shared__ float hs[2][HID];
    __shared__ float red[2][2][2];
    const int j = threadIdx.x & 127;
    const int local_n = threadIdx.x >> 7;
    const int wavehalf = (threadIdx.x >> 6) & 1;
    float w[HID];
#pragma unroll
    for (int k = 0; k < HID; ++k) w[k] = W1[k * HID2 + j];
    const float bias = b1[j];
    const float g = g1[j];
    const float be = be1[j];

    for (int base = blockIdx.x * 2; base < N_NODES; base += gridDim.x * 2) {
        __syncthreads();
        if (threadIdx.x < 128) {
            int nn = threadIdx.x >> 6, c = threadIdx.x & 63;
            int idx = (base + nn) * HID + c;
            hs[nn][c] = agg[idx] + zin[idx];
        }
        __syncthreads();
        const int n = base + local_n;
        float u = bias;
#pragma unroll
        for (int k4 = 0; k4 < HID / 4; ++k4) {
            float4 hv = ((const float4*)hs[local_n])[k4];
            u = fmaf(hv.x, w[k4 * 4 + 0], u);
            u = fmaf(hv.y, w[k4 * 4 + 1], u);
            u = fmaf(hv.z, w[k4 * 4 + 2], u);
            u = fmaf(hv.w, w[k4 * 4 + 3], u);
        }
        float ps_ = u;
#pragma unroll
        for (int o = 1; o < 64; o <<= 1) ps_ += __shfl_xor(ps_, o, 64);
        if ((threadIdx.x & 63) == 0) red[local_n][0][wavehalf] = ps_;
        __syncthreads();
        const float mu = (red[local_n][0][0] + red[local_n][0][1]) * (1.f / 128.f);
        const float d = u - mu;
        float q = d * d;
#pragma unroll
        for (int o = 1; o < 64; o <<= 1) q += __shfl_xor(q, o, 64);
        if ((threadIdx.x & 63) == 0) red[local_n][1][wavehalf] = q;
        __syncthreads();
        const float var = (red[local_n][1][0] + red[local_n][1][1]) * (1.f / 128.f);
        const float y = d * rsqrtf(var + 1e-5f) * g + be;
        v[n * HID2 + j] = y > 0.f ? y : 0.f;
    }
}

// ---------------------------------------------------------------------------
// mm2: out2 = v@W2 + b2 ; h = (residual? h:0) + out2 ;
//      z = relu(LN64(h)*gz+bz)
// ---------------------------------------------------------------------------
__global__ __launch_bounds__(256, 2) void node_mm2_kernel(
    const float* __restrict__ v,
    const float* __restrict__ W2, const float* __restrict__ b2,
    const float* __restrict__ lng, const float* __restrict__ lnb,
    float* __restrict__ h, float* __restrict__ z, int residual)
{
    __shared__ float vs[4][HID2];
    const int c = threadIdx.x & 63;
    const int local_n = threadIdx.x >> 6;
    float w[HID2];
#pragma unroll
    for (int k = 0; k < HID2; ++k) w[k] = W2[k * HID + c];
    const float bias = b2[c];
    const float g = lng[c];
    const float be = lnb[c];

    for (int base = blockIdx.x * 4; base < N_NODES; base += gridDim.x * 4) {
        __syncthreads();
#pragma unroll
        for (int i = 0; i < 2; ++i) {
            int idx = threadIdx.x + i * 256;
            int nn = idx >> 7, kk = idx & 127;
            vs[nn][kk] = v[(base + nn) * HID2 + kk];
        }
        __syncthreads();
        const int n = base + local_n;
        float acc = bias;
#pragma unroll
        for (int k4 = 0; k4 < HID2 / 4; ++k4) {
            float4 vv = ((const float4*)vs[local_n])[k4];
            acc = fmaf(vv.x, w[k4 * 4 + 0], acc);
            acc = fmaf(vv.y, w[k4 * 4 + 1], acc);
            acc = fmaf(vv.z, w[k4 * 4 + 2], acc);
            acc = fmaf(vv.w, w[k4 * 4 + 3], acc);
        }
        const float hn = residual ? (h[n * HID + c] + acc) : acc;
        h[n * HID + c] = hn;
        float ps_ = hn;
#pragma unroll
        for (int o = 1; o < 64; o <<= 1) ps_ += __shfl_xor(ps_, o, 64);
        const float mu = ps_ * (1.f / 64.f);
        const float d = hn - mu;
        float q = d * d;
#pragma unroll
        for (int o = 1; o < 64; o <<= 1) q += __shfl_xor(q, o, 64);
        const float var = q * (1.f / 64.f);
        const float y = d * rsqrtf(var + 1e-5f) * g + be;
        z[n * HID + c] = y > 0.f ? y : 0.f;
    }
}

// ---------------------------------------------------------------------------
// out = z @ lin_W + lin_b      [N,64]@[64,8]
// ---------------------------------------------------------------------------
__global__ __launch_bounds__(256, 4) void final_kernel(
    const float* __restrict__ z, const float* __restrict__ Wl,
    const float* __restrict__ bl, float* __restrict__ out)
{
    __shared__ float wl[HID * OUT_DIM];
    for (int i = threadIdx.x; i < HID * OUT_DIM; i += 256) wl[i] = Wl[i];
    __syncthreads();
    const int total = N_NODES * OUT_DIM;
    for (int idx = blockIdx.x * 256 + threadIdx.x; idx < total;
         idx += gridDim.x * 256) {
        const int n = idx >> 3, o = idx & 7;
        const float4* zp4 = (const float4*)(z + n * HID);
        float acc = bl[o];
#pragma unroll
        for (int k4 = 0; k4 < HID / 4; ++k4) {
            float4 zv = zp4[k4];
            acc = fmaf(zv.x, wl[(k4 * 4 + 0) * OUT_DIM + o], acc);
            acc = fmaf(zv.y, wl[(k4 * 4 + 1) * OUT_DIM + o], acc);
            acc = fmaf(zv.z, wl[(k4 * 4 + 2) * OUT_DIM + o], acc);
            acc = fmaf(zv.w, wl[(k4 * 4 + 3) * OUT_DIM + o], acc);
        }
        out[idx] = acc;
    }
}

// ---------------------------------------------------------------------------
extern "C" void kernel_launch(void* const* d_in, const int* in_sizes, int n_in,
                              void* d_out, int out_size, void* d_ws, size_t ws_size,
                              hipStream_t stream)
{
    const float* x         = (const float*)d_in[0];
    const float* edge_attr = (const float*)d_in[1];
    const float* node_W    = (const float*)d_in[2];
    const float* node_b    = (const float*)d_in[3];
    const float* edge_W    = (const float*)d_in[4];
    const float* edge_b    = (const float*)d_in[5];
    const float* conv_t    = (const float*)d_in[6];
    const float* conv_W1   = (const float*)d_in[7];
    const float* conv_b1   = (const float*)d_in[8];
    const float* conv_g1   = (const float*)d_in[9];
    const float* conv_be1  = (const float*)d_in[10];
    const float* conv_W2   = (const float*)d_in[11];
    const float* conv_b2   = (const float*)d_in[12];
    const float* ln_g      = (const float*)d_in[13];
    const float* ln_b      = (const float*)d_in[14];
    const float* lin_W     = (const float*)d_in[15];
    const float* lin_b     = (const float*)d_in[16];
    const int*   edge_index= (const int*)d_in[17];
    const int*   srcs = edge_index;
    const int*   dsts = edge_index + N_EDGES;
    float* out = (float*)d_out;

    // workspace layout (~173.4 MB)
    float* h   = (float*)d_ws;                    // N*64
    float* z   = h   + N_NODES * HID;             // N*64
    float* agg = z   + N_NODES * HID;             // N*64
    float* v   = agg + N_NODES * HID;             // N*128
    __half* eah = (__half*)(v + N_NODES * HID2);  // E*64 half
    int* deg     = (int*)(eah + (size_t)N_EDGES * HID); // N
    int* offsets = deg + N_NODES;                 // N+1
    int* cursor  = offsets + N_NODES + 1;         // N
    int* sid     = cursor + N_NODES;              // E
    int* ssrc    = sid + N_EDGES;                 // E

    // ---- counting sort of edges by dst (once per call) ----
    hipMemsetAsync(deg, 0, (size_t)N_NODES * sizeof(int), stream);
    hist_kernel<<<1024, 256, 0, stream>>>(dsts, deg);
    scan_kernel<<<1, 1024, 0, stream>>>(deg, offsets);
    hipMemcpyAsync(cursor, offsets, (size_t)N_NODES * sizeof(int),
                   hipMemcpyDeviceToDevice, stream);
    scatter_kernel<<<1024, 256, 0, stream>>>(srcs, dsts, cursor, sid, ssrc);

    node_proj_kernel<<<2048, 256, 0, stream>>>(x, node_W, node_b, h);
    edge_emb_kernel<<<4096, 256, 0, stream>>>(edge_attr, edge_W, edge_b, sid, eah);

    for (int layer = 0; layer < N_LAYERS; ++layer) {
        const float* zin = (layer == 0) ? h : z;
        edge_agg_kernel<<<4096, 256, 0, stream>>>(zin, eah, ssrc, offsets,
                                                  conv_t, layer, agg);
        node_mm1_kernel<<<2048, 256, 0, stream>>>(
            agg, zin,
            conv_W1 + (size_t)layer * HID * HID2, conv_b1 + layer * HID2,
            conv_g1 + layer * HID2, conv_be1 + layer * HID2, v);
        const float* gz = (layer < N_LAYERS - 1) ? (ln_g + (layer + 1) * HID) : ln_g;
        const float* bz = (layer < N_LAYERS - 1) ? (ln_b + (layer + 1) * HID) : ln_b;
        node_mm2_kernel<<<2048, 256, 0, stream>>>(
            v, conv_W2 + (size_t)layer * HID2 * HID, conv_b2 + layer * HID,
            gz, bz, h, z, layer > 0 ? 1 : 0);
    }
    final_kernel<<<1024, 256, 0, stream>>>(z, lin_W, lin_b, out);
}

// Round 3
// 930.369 us; speedup vs baseline: 2.1242x; 1.1239x over previous
//
#include <hip/hip_runtime.h>
#include <hip/hip_fp16.h>

#define N_NODES 50000
#define N_EDGES 800000
#define IN_DIM  128
#define EDGE_DIM 16
#define HID     64
#define HID2    128
#define OUT_DIM 8
#define N_LAYERS 4

// ---------------------------------------------------------------------------
// Counting sort of edges by dst: histogram -> exclusive scan -> scatter.
// ---------------------------------------------------------------------------
__global__ __launch_bounds__(256, 4) void hist_kernel(
    const int* __restrict__ dsts, int* __restrict__ deg)
{
    for (int e = blockIdx.x * 256 + threadIdx.x; e < N_EDGES;
         e += gridDim.x * 256)
        atomicAdd(&deg[dsts[e]], 1);
}

// single block, 1024 threads; exclusive scan of deg[0..N) -> offsets[0..N]
__global__ __launch_bounds__(1024, 1) void scan_kernel(
    const int* __restrict__ deg, int* __restrict__ offsets)
{
    __shared__ int part[1024];
    const int t = threadIdx.x;
    const int CHUNK = (N_NODES + 1023) / 1024;           // 49
    const int lo = t * CHUNK;
    const int hi = min(lo + CHUNK, N_NODES);
    int sum = 0;
    for (int i = lo; i < hi; ++i) sum += deg[i];
    part[t] = sum;
    __syncthreads();
    for (int off = 1; off < 1024; off <<= 1) {           // Hillis-Steele incl.
        int v_ = (t >= off) ? part[t - off] : 0;
        __syncthreads();
        part[t] += v_;
        __syncthreads();
    }
    int run = (t > 0) ? part[t - 1] : 0;                 // exclusive base
    for (int i = lo; i < hi; ++i) { offsets[i] = run; run += deg[i]; }
    if (t == 1023) offsets[N_NODES] = part[1023];        // total
}

// pos = cursor[dst]++ ; inv[e] = pos (streaming) ; ssrc[pos] = src[e]
__global__ __launch_bounds__(256, 4) void scatter_kernel(
    const int* __restrict__ srcs, const int* __restrict__ dsts,
    int* __restrict__ cursor, int* __restrict__ inv, int* __restrict__ ssrc)
{
    for (int e = blockIdx.x * 256 + threadIdx.x; e < N_EDGES;
         e += gridDim.x * 256) {
        const int d = dsts[e];
        const int pos = atomicAdd(&cursor[d], 1);
        inv[e] = pos;
        ssrc[pos] = srcs[e];
    }
}

// ---------------------------------------------------------------------------
// h0 = x @ node_W + node_b      [N,128]@[128,64]; also fp16 copy for gathers
// ---------------------------------------------------------------------------
__global__ __launch_bounds__(256, 2) void node_proj_kernel(
    const float* __restrict__ x, const float* __restrict__ W,
    const float* __restrict__ b, float* __restrict__ h, __half* __restrict__ zh)
{
    __shared__ float xs[4][IN_DIM];
    const int c = threadIdx.x & 63;
    const int local_n = threadIdx.x >> 6;
    float w[IN_DIM];
#pragma unroll
    for (int k = 0; k < IN_DIM; ++k) w[k] = W[k * HID + c];
    const float bias = b[c];

    for (int base = blockIdx.x * 4; base < N_NODES; base += gridDim.x * 4) {
        __syncthreads();
#pragma unroll
        for (int i = 0; i < 2; ++i) {
            int idx = threadIdx.x + i * 256;
            int nn = idx >> 7, kk = idx & 127;
            xs[nn][kk] = x[(base + nn) * IN_DIM + kk];
        }
        __syncthreads();
        const int n = base + local_n;
        float acc = bias;
#pragma unroll
        for (int k4 = 0; k4 < IN_DIM / 4; ++k4) {
            float4 xv = ((const float4*)xs[local_n])[k4];
            acc = fmaf(xv.x, w[k4 * 4 + 0], acc);
            acc = fmaf(xv.y, w[k4 * 4 + 1], acc);
            acc = fmaf(xv.z, w[k4 * 4 + 2], acc);
            acc = fmaf(xv.w, w[k4 * 4 + 3], acc);
        }
        h[n * HID + c] = acc;
        zh[n * HID + c] = __float2half(acc);
    }
}

// ---------------------------------------------------------------------------
// eah[inv[e]] = fp16( edge_attr[e] @ edge_W + edge_b )
// ORIGINAL edge order: ea/inv loads are streaming + wave-uniform (scalar);
// only the store address is data-dependent -> no load latency chain.
// ---------------------------------------------------------------------------
__global__ __launch_bounds__(256, 4) void edge_emb_kernel(
    const float* __restrict__ ea, const float* __restrict__ W,
    const float* __restrict__ b, const int* __restrict__ inv,
    __half* __restrict__ eah)
{
    const int lane = threadIdx.x & 63;
    const int wave0 =
        __builtin_amdgcn_readfirstlane(blockIdx.x * 4 + (threadIdx.x >> 6));
    const int nwaves = gridDim.x * 4;
    float w[EDGE_DIM];
#pragma unroll
    for (int k = 0; k < EDGE_DIM; ++k) w[k] = W[k * HID + lane];
    const float bias = b[lane];

    for (int e = wave0; e < N_EDGES; e += nwaves) {
        const int pos = inv[e];                      // wave-uniform scalar load
        const float* ap = ea + (size_t)e * EDGE_DIM; // wave-uniform scalar load
        float acc = bias;
#pragma unroll
        for (int k = 0; k < EDGE_DIM; ++k)
            acc = fmaf(ap[k], w[k], acc);
        eah[(size_t)pos * HID + lane] = __float2half(acc);
    }
}

// ---------------------------------------------------------------------------
// Segmented softmax-aggregate, one wave per node, ILP-4 gather batching.
// agg[n] = sum(m*e)/(sum(e)+1e-16), m = relu(zh[src]+ea)+eps, e = exp(m*t)
// ---------------------------------------------------------------------------
__global__ __launch_bounds__(256, 4) void edge_agg_kernel(
    const __half* __restrict__ zh, const __half* __restrict__ eah,
    const int* __restrict__ ssrc, const int* __restrict__ offsets,
    const float* __restrict__ conv_t, int layer, float* __restrict__ agg)
{
    const int lane = threadIdx.x & 63;
    const int wave0 =
        __builtin_amdgcn_readfirstlane(blockIdx.x * 4 + (threadIdx.x >> 6));
    const int nwaves = gridDim.x * 4;
    const float t = conv_t[layer];

    for (int n = wave0; n < N_NODES; n += nwaves) {
        const int s0 = offsets[n];
        const int s1 = offsets[n + 1];
        float S = 0.f, P = 0.f;
        int i = s0;
        for (; i + 4 <= s1; i += 4) {
            const int a0 = ssrc[i + 0];              // scalar loads (uniform)
            const int a1 = ssrc[i + 1];
            const int a2 = ssrc[i + 2];
            const int a3 = ssrc[i + 3];
            float z0 = __half2float(zh[(size_t)a0 * HID + lane]);  // 4 indep
            float z1 = __half2float(zh[(size_t)a1 * HID + lane]);  // gathers
            float z2 = __half2float(zh[(size_t)a2 * HID + lane]);
            float z3 = __half2float(zh[(size_t)a3 * HID + lane]);
            float e0 = __half2float(eah[(size_t)(i + 0) * HID + lane]);
            float e1 = __half2float(eah[(size_t)(i + 1) * HID + lane]);
            float e2 = __half2float(eah[(size_t)(i + 2) * HID + lane]);
            float e3 = __half2float(eah[(size_t)(i + 3) * HID + lane]);
            float m0 = fmaxf(z0 + e0, 0.f) + 1e-7f;
            float m1 = fmaxf(z1 + e1, 0.f) + 1e-7f;
            float m2 = fmaxf(z2 + e2, 0.f) + 1e-7f;
            float m3 = fmaxf(z3 + e3, 0.f) + 1e-7f;
            float x0 = __expf(m0 * t);
            float x1 = __expf(m1 * t);
            float x2 = __expf(m2 * t);
            float x3 = __expf(m3 * t);
            S += (x0 + x1) + (x2 + x3);
            P = fmaf(m0, x0, fmaf(m1, x1, fmaf(m2, x2, fmaf(m3, x3, P))));
        }
        for (; i < s1; ++i) {
            const int a = ssrc[i];
            float z = __half2float(zh[(size_t)a * HID + lane]);
            float e = __half2float(eah[(size_t)i * HID + lane]);
            float m = fmaxf(z + e, 0.f) + 1e-7f;
            float x = __expf(m * t);
            S += x;
            P = fmaf(m, x, P);
        }
        agg[(size_t)n * HID + lane] = P / (S + 1e-16f);
    }
}

// ---------------------------------------------------------------------------
// mm1: hin = agg + zin ; u = hin@W1 + b1 ; v = relu(LN128(u)*g1+be1)
// ---------------------------------------------------------------------------
__global__ __launch_bounds__(256, 2) void node_mm1_kernel(
    const float* __restrict__ agg, const float* __restrict__ zin,
    const float* __restrict__ W1, const float* __restrict__ b1,
    const float* __restrict__ g1, const float* __restrict__ be1,
    float* __restrict__ v)
{
    __shared__ float hs[2][HID];
    __shared__ float red[2][2][2];
    const int j = threadIdx.x & 127;
    const int local_n = threadIdx.x >> 7;
    const int wavehalf = (threadIdx.x >> 6) & 1;
    float w[HID];
#pragma unroll
    for (int k = 0; k < HID; ++k) w[k] = W1[k * HID2 + j];
    const float bias = b1[j];
    const float g = g1[j];
    const float be = be1[j];

    for (int base = blockIdx.x * 2; base < N_NODES; base += gridDim.x * 2) {
        __syncthreads();
        if (threadIdx.x < 128) {
            int nn = threadIdx.x >> 6, c = threadIdx.x & 63;
            int idx = (base + nn) * HID + c;
            hs[nn][c] = agg[idx] + zin[idx];
        }
        __syncthreads();
        const int n = base + local_n;
        float u = bias;
#pragma unroll
        for (int k4 = 0; k4 < HID / 4; ++k4) {
            float4 hv = ((const float4*)hs[local_n])[k4];
            u = fmaf(hv.x, w[k4 * 4 + 0], u);
            u = fmaf(hv.y, w[k4 * 4 + 1], u);
            u = fmaf(hv.z, w[k4 * 4 + 2], u);
            u = fmaf(hv.w, w[k4 * 4 + 3], u);
        }
        float ps_ = u;
#pragma unroll
        for (int o = 1; o < 64; o <<= 1) ps_ += __shfl_xor(ps_, o, 64);
        if ((threadIdx.x & 63) == 0) red[local_n][0][wavehalf] = ps_;
        __syncthreads();
        const float mu = (red[local_n][0][0] + red[local_n][0][1]) * (1.f / 128.f);
        const float d = u - mu;
        float q = d * d;
#pragma unroll
        for (int o = 1; o < 64; o <<= 1) q += __shfl_xor(q, o, 64);
        if ((threadIdx.x & 63) == 0) red[local_n][1][wavehalf] = q;
        __syncthreads();
        const float var = (red[local_n][1][0] + red[local_n][1][1]) * (1.f / 128.f);
        const float y = d * rsqrtf(var + 1e-5f) * g + be;
        v[n * HID2 + j] = y > 0.f ? y : 0.f;
    }
}

// ---------------------------------------------------------------------------
// mm2: out2 = v@W2 + b2 ; h = (residual? h:0) + out2 ;
//      z = relu(LN64(h)*gz+bz) ; zh = fp16(z)
// ---------------------------------------------------------------------------
__global__ __launch_bounds__(256, 2) void node_mm2_kernel(
    const float* __restrict__ v,
    const float* __restrict__ W2, const float* __restrict__ b2,
    const float* __restrict__ lng, const float* __restrict__ lnb,
    float* __restrict__ h, float* __restrict__ z, __half* __restrict__ zh,
    int residual)
{
    __shared__ float vs[4][HID2];
    const int c = threadIdx.x & 63;
    const int local_n = threadIdx.x >> 6;
    float w[HID2];
#pragma unroll
    for (int k = 0; k < HID2; ++k) w[k] = W2[k * HID + c];
    const float bias = b2[c];
    const float g = lng[c];
    const float be = lnb[c];

    for (int base = blockIdx.x * 4; base < N_NODES; base += gridDim.x * 4) {
        __syncthreads();
#pragma unroll
        for (int i = 0; i < 2; ++i) {
            int idx = threadIdx.x + i * 256;
            int nn = idx >> 7, kk = idx & 127;
            vs[nn][kk] = v[(base + nn) * HID2 + kk];
        }
        __syncthreads();
        const int n = base + local_n;
        float acc = bias;
#pragma unroll
        for (int k4 = 0; k4 < HID2 / 4; ++k4) {
            float4 vv = ((const float4*)vs[local_n])[k4];
            acc = fmaf(vv.x, w[k4 * 4 + 0], acc);
            acc = fmaf(vv.y, w[k4 * 4 + 1], acc);
            acc = fmaf(vv.z, w[k4 * 4 + 2], acc);
            acc = fmaf(vv.w, w[k4 * 4 + 3], acc);
        }
        const float hn = residual ? (h[n * HID + c] + acc) : acc;
        h[n * HID + c] = hn;
        float ps_ = hn;
#pragma unroll
        for (int o = 1; o < 64; o <<= 1) ps_ += __shfl_xor(ps_, o, 64);
        const float mu = ps_ * (1.f / 64.f);
        const float d = hn - mu;
        float q = d * d;
#pragma unroll
        for (int o = 1; o < 64; o <<= 1) q += __shfl_xor(q, o, 64);
        const float var = q * (1.f / 64.f);
        const float y = d * rsqrtf(var + 1e-5f) * g + be;
        const float zr = y > 0.f ? y : 0.f;
        z[n * HID + c] = zr;
        zh[n * HID + c] = __float2half(zr);
    }
}

// ---------------------------------------------------------------------------
// out = z @ lin_W + lin_b      [N,64]@[64,8]
// ---------------------------------------------------------------------------
__global__ __launch_bounds__(256, 4) void final_kernel(
    const float* __restrict__ z, const float* __restrict__ Wl,
    const float* __restrict__ bl, float* __restrict__ out)
{
    __shared__ float wl[HID * OUT_DIM];
    for (int i = threadIdx.x; i < HID * OUT_DIM; i += 256) wl[i] = Wl[i];
    __syncthreads();
    const int total = N_NODES * OUT_DIM;
    for (int idx = blockIdx.x * 256 + threadIdx.x; idx < total;
         idx += gridDim.x * 256) {
        const int n = idx >> 3, o = idx & 7;
        const float4* zp4 = (const float4*)(z + n * HID);
        float acc = bl[o];
#pragma unroll
        for (int k4 = 0; k4 < HID / 4; ++k4) {
            float4 zv = zp4[k4];
            acc = fmaf(zv.x, wl[(k4 * 4 + 0) * OUT_DIM + o], acc);
            acc = fmaf(zv.y, wl[(k4 * 4 + 1) * OUT_DIM + o], acc);
            acc = fmaf(zv.z, wl[(k4 * 4 + 2) * OUT_DIM + o], acc);
            acc = fmaf(zv.w, wl[(k4 * 4 + 3) * OUT_DIM + o], acc);
        }
        out[idx] = acc;
    }
}

// ---------------------------------------------------------------------------
extern "C" void kernel_launch(void* const* d_in, const int* in_sizes, int n_in,
                              void* d_out, int out_size, void* d_ws, size_t ws_size,
                              hipStream_t stream)
{
    const float* x         = (const float*)d_in[0];
    const float* edge_attr = (const float*)d_in[1];
    const float* node_W    = (const float*)d_in[2];
    const float* node_b    = (const float*)d_in[3];
    const float* edge_W    = (const float*)d_in[4];
    const float* edge_b    = (const float*)d_in[5];
    const float* conv_t    = (const float*)d_in[6];
    const float* conv_W1   = (const float*)d_in[7];
    const float* conv_b1   = (const float*)d_in[8];
    const float* conv_g1   = (const float*)d_in[9];
    const float* conv_be1  = (const float*)d_in[10];
    const float* conv_W2   = (const float*)d_in[11];
    const float* conv_b2   = (const float*)d_in[12];
    const float* ln_g      = (const float*)d_in[13];
    const float* ln_b      = (const float*)d_in[14];
    const float* lin_W     = (const float*)d_in[15];
    const float* lin_b     = (const float*)d_in[16];
    const int*   edge_index= (const int*)d_in[17];
    const int*   srcs = edge_index;
    const int*   dsts = edge_index + N_EDGES;
    float* out = (float*)d_out;

    // workspace layout (~180 MB)
    float* h   = (float*)d_ws;                    // N*64
    float* z   = h   + N_NODES * HID;             // N*64
    float* agg = z   + N_NODES * HID;             // N*64
    float* v   = agg + N_NODES * HID;             // N*128
    __half* zh  = (__half*)(v + N_NODES * HID2);  // N*64 half
    __half* eah = zh + (size_t)N_NODES * HID;     // E*64 half
    int* deg     = (int*)(eah + (size_t)N_EDGES * HID); // N
    int* offsets = deg + N_NODES;                 // N+1
    int* cursor  = offsets + N_NODES + 1;         // N
    int* inv     = cursor + N_NODES;              // E
    int* ssrc    = inv + N_EDGES;                 // E

    // ---- counting sort of edges by dst (once per call) ----
    hipMemsetAsync(deg, 0, (size_t)N_NODES * sizeof(int), stream);
    hist_kernel<<<1024, 256, 0, stream>>>(dsts, deg);
    scan_kernel<<<1, 1024, 0, stream>>>(deg, offsets);
    hipMemcpyAsync(cursor, offsets, (size_t)N_NODES * sizeof(int),
                   hipMemcpyDeviceToDevice, stream);
    scatter_kernel<<<1024, 256, 0, stream>>>(srcs, dsts, cursor, inv, ssrc);

    node_proj_kernel<<<2048, 256, 0, stream>>>(x, node_W, node_b, h, zh);
    edge_emb_kernel<<<4096, 256, 0, stream>>>(edge_attr, edge_W, edge_b, inv, eah);

    for (int layer = 0; layer < N_LAYERS; ++layer) {
        const float* zin = (layer == 0) ? h : z;
        edge_agg_kernel<<<12500, 256, 0, stream>>>(zh, eah, ssrc, offsets,
                                                   conv_t, layer, agg);
        node_mm1_kernel<<<2048, 256, 0, stream>>>(
            agg, zin,
            conv_W1 + (size_t)layer * HID * HID2, conv_b1 + layer * HID2,
            conv_g1 + layer * HID2, conv_be1 + layer * HID2, v);
        const float* gz = (layer < N_LAYERS - 1) ? (ln_g + (layer + 1) * HID) : ln_g;
        const float* bz = (layer < N_LAYERS - 1) ? (ln_b + (layer + 1) * HID) : ln_b;
        node_mm2_kernel<<<2048, 256, 0, stream>>>(
            v, conv_W2 + (size_t)layer * HID2 * HID, conv_b2 + layer * HID,
            gz, bz, h, z, zh, layer > 0 ? 1 : 0);
    }
    final_kernel<<<1024, 256, 0, stream>>>(z, lin_W, lin_b, out);
}

// Round 4
// 875.947 us; speedup vs baseline: 2.2562x; 1.0621x over previous
//
#include <hip/hip_runtime.h>
#include <hip/hip_fp16.h>

#define N_NODES 50000
#define N_EDGES 800000
#define IN_DIM  128
#define EDGE_DIM 16
#define HID     64
#define HID2    128
#define OUT_DIM 8
#define N_LAYERS 4

__device__ __forceinline__ float rlf(float v, int l) {
    return __int_as_float(__builtin_amdgcn_readlane(__float_as_int(v), l));
}

// ---------------------------------------------------------------------------
// Counting sort of edges by dst: histogram -> exclusive scan -> scatter.
// ---------------------------------------------------------------------------
__global__ __launch_bounds__(256, 4) void hist_kernel(
    const int* __restrict__ dsts, int* __restrict__ deg)
{
    for (int e = blockIdx.x * 256 + threadIdx.x; e < N_EDGES;
         e += gridDim.x * 256)
        atomicAdd(&deg[dsts[e]], 1);
}

// single block, 1024 threads; exclusive scan of deg[0..N) -> offsets[0..N]
__global__ __launch_bounds__(1024, 1) void scan_kernel(
    const int* __restrict__ deg, int* __restrict__ offsets)
{
    __shared__ int part[1024];
    const int t = threadIdx.x;
    const int CHUNK = (N_NODES + 1023) / 1024;           // 49
    const int lo = t * CHUNK;
    const int hi = min(lo + CHUNK, N_NODES);
    int sum = 0;
    for (int i = lo; i < hi; ++i) sum += deg[i];
    part[t] = sum;
    __syncthreads();
    for (int off = 1; off < 1024; off <<= 1) {           // Hillis-Steele incl.
        int v_ = (t >= off) ? part[t - off] : 0;
        __syncthreads();
        part[t] += v_;
        __syncthreads();
    }
    int run = (t > 0) ? part[t - 1] : 0;                 // exclusive base
    for (int i = lo; i < hi; ++i) { offsets[i] = run; run += deg[i]; }
    if (t == 1023) offsets[N_NODES] = part[1023];        // total
}

// pos = cursor[dst]++ ; inv[e] = pos (streaming) ; ssrc[pos] = src[e]
__global__ __launch_bounds__(256, 4) void scatter_kernel(
    const int* __restrict__ srcs, const int* __restrict__ dsts,
    int* __restrict__ cursor, int* __restrict__ inv, int* __restrict__ ssrc)
{
    for (int e = blockIdx.x * 256 + threadIdx.x; e < N_EDGES;
         e += gridDim.x * 256) {
        const int d = dsts[e];
        const int pos = atomicAdd(&cursor[d], 1);
        inv[e] = pos;
        ssrc[pos] = srcs[e];
    }
}

// ---------------------------------------------------------------------------
// h0 = x @ node_W + node_b      [N,128]@[128,64]; also fp16 copy for gathers
// ---------------------------------------------------------------------------
__global__ __launch_bounds__(256, 2) void node_proj_kernel(
    const float* __restrict__ x, const float* __restrict__ W,
    const float* __restrict__ b, float* __restrict__ h, __half* __restrict__ zh)
{
    __shared__ float xs[4][IN_DIM];
    const int c = threadIdx.x & 63;
    const int local_n = threadIdx.x >> 6;
    float w[IN_DIM];
#pragma unroll
    for (int k = 0; k < IN_DIM; ++k) w[k] = W[k * HID + c];
    const float bias = b[c];

    for (int base = blockIdx.x * 4; base < N_NODES; base += gridDim.x * 4) {
        __syncthreads();
#pragma unroll
        for (int i = 0; i < 2; ++i) {
            int idx = threadIdx.x + i * 256;
            int nn = idx >> 7, kk = idx & 127;
            xs[nn][kk] = x[(base + nn) * IN_DIM + kk];
        }
        __syncthreads();
        const int n = base + local_n;
        float acc = bias;
#pragma unroll
        for (int k4 = 0; k4 < IN_DIM / 4; ++k4) {
            float4 xv = ((const float4*)xs[local_n])[k4];
            acc = fmaf(xv.x, w[k4 * 4 + 0], acc);
            acc = fmaf(xv.y, w[k4 * 4 + 1], acc);
            acc = fmaf(xv.z, w[k4 * 4 + 2], acc);
            acc = fmaf(xv.w, w[k4 * 4 + 3], acc);
        }
        h[n * HID + c] = acc;
        zh[n * HID + c] = __float2half(acc);
    }
}

// ---------------------------------------------------------------------------
// edge embedding, fully vectorized: tile = 64 edges per wave (12500 tiles
// exactly). All loads coalesced VMEM; attrs broadcast with v_readlane;
// per-edge output is one contiguous 128B half store at eah[inv[e]].
// ---------------------------------------------------------------------------
__device__ __forceinline__ void emb_quarter(
    const float4 q, int qbase, int posv, const float* w, float bias, int lane,
    __half* __restrict__ eah)
{
#pragma unroll
    for (int jj = 0; jj < 16; ++jj) {
        const int lb = jj * 4;
        float acc = bias;
        acc = fmaf(rlf(q.x, lb + 0), w[0],  acc);
        acc = fmaf(rlf(q.y, lb + 0), w[1],  acc);
        acc = fmaf(rlf(q.z, lb + 0), w[2],  acc);
        acc = fmaf(rlf(q.w, lb + 0), w[3],  acc);
        acc = fmaf(rlf(q.x, lb + 1), w[4],  acc);
        acc = fmaf(rlf(q.y, lb + 1), w[5],  acc);
        acc = fmaf(rlf(q.z, lb + 1), w[6],  acc);
        acc = fmaf(rlf(q.w, lb + 1), w[7],  acc);
        acc = fmaf(rlf(q.x, lb + 2), w[8],  acc);
        acc = fmaf(rlf(q.y, lb + 2), w[9],  acc);
        acc = fmaf(rlf(q.z, lb + 2), w[10], acc);
        acc = fmaf(rlf(q.w, lb + 2), w[11], acc);
        acc = fmaf(rlf(q.x, lb + 3), w[12], acc);
        acc = fmaf(rlf(q.y, lb + 3), w[13], acc);
        acc = fmaf(rlf(q.z, lb + 3), w[14], acc);
        acc = fmaf(rlf(q.w, lb + 3), w[15], acc);
        const int pos = __builtin_amdgcn_readlane(posv, qbase + jj);
        eah[(size_t)pos * HID + lane] = __float2half(acc);
    }
}

__global__ __launch_bounds__(256, 4) void edge_emb_kernel(
    const float* __restrict__ ea, const float* __restrict__ W,
    const float* __restrict__ b, const int* __restrict__ inv,
    __half* __restrict__ eah)
{
    const int lane = threadIdx.x & 63;
    const int wave = (blockIdx.x * 256 + threadIdx.x) >> 6;
    const int nwaves = gridDim.x * 4;
    const int NTILES = N_EDGES / 64;                 // 12500, exact
    float w[EDGE_DIM];
#pragma unroll
    for (int k = 0; k < EDGE_DIM; ++k) w[k] = W[k * HID + lane];
    const float bias = b[lane];

    for (int tile = wave; tile < NTILES; tile += nwaves) {
        const int e0 = tile * 64;
        const int posv = inv[e0 + lane];             // coalesced vector load
        const float4* ap = (const float4*)ea + (size_t)e0 * 4;
        float4 q0 = ap[lane];                        // edges  0..15
        float4 q1 = ap[64 + lane];                   // edges 16..31
        float4 q2 = ap[128 + lane];                  // edges 32..47
        float4 q3 = ap[192 + lane];                  // edges 48..63
        emb_quarter(q0, 0,  posv, w, bias, lane, eah);
        emb_quarter(q1, 16, posv, w, bias, lane, eah);
        emb_quarter(q2, 32, posv, w, bias, lane, eah);
        emb_quarter(q3, 48, posv, w, bias, lane, eah);
    }
}

// ---------------------------------------------------------------------------
// Segmented softmax-aggregate, one wave per node. ssrc loaded 64-wide and
// broadcast via v_readlane (dynamic uniform index); zh gathers batched
// 8-deep (8 outstanding 128B line reads); eah streaming.
// ---------------------------------------------------------------------------
__global__ __launch_bounds__(256, 4) void edge_agg_kernel(
    const __half* __restrict__ zh, const __half* __restrict__ eah,
    const int* __restrict__ ssrc, const int* __restrict__ offsets,
    const float* __restrict__ conv_t, int layer, float* __restrict__ agg)
{
    const int lane = threadIdx.x & 63;
    const int wave = (blockIdx.x * 256 + threadIdx.x) >> 6;
    const int nwaves = gridDim.x * 4;
    const float t = conv_t[layer];

    for (int n = wave; n < N_NODES; n += nwaves) {
        const int s0 = offsets[n];
        const int s1 = offsets[n + 1];
        float S = 0.f, P = 0.f;
        for (int base = s0; base < s1; base += 64) {
            const int cnt = min(64, s1 - base);
            const int srcv = ssrc[base + (lane < cnt ? lane : cnt - 1)];
            int j = 0;
            for (; j + 8 <= cnt; j += 8) {
                float z[8], e[8];
#pragma unroll
                for (int k = 0; k < 8; ++k) {
                    const int a = __builtin_amdgcn_readlane(srcv, j + k);
                    z[k] = __half2float(zh[(size_t)a * HID + lane]);
                }
#pragma unroll
                for (int k = 0; k < 8; ++k)
                    e[k] = __half2float(eah[(size_t)(base + j + k) * HID + lane]);
#pragma unroll
                for (int k = 0; k < 8; ++k) {
                    const float m = fmaxf(z[k] + e[k], 0.f) + 1e-7f;
                    const float xx = __expf(m * t);
                    S += xx;
                    P = fmaf(m, xx, P);
                }
            }
            for (; j < cnt; ++j) {
                const int a = __builtin_amdgcn_readlane(srcv, j);
                const float zz = __half2float(zh[(size_t)a * HID + lane]);
                const float ee = __half2float(eah[(size_t)(base + j) * HID + lane]);
                const float m = fmaxf(zz + ee, 0.f) + 1e-7f;
                const float xx = __expf(m * t);
                S += xx;
                P = fmaf(m, xx, P);
            }
        }
        agg[(size_t)n * HID + lane] = P / (S + 1e-16f);
    }
}

// ---------------------------------------------------------------------------
// mm1: hin = agg + zin ; u = hin@W1 + b1 ; v = relu(LN128(u)*g1+be1)
// ---------------------------------------------------------------------------
__global__ __launch_bounds__(256, 2) void node_mm1_kernel(
    const float* __restrict__ agg, const float* __restrict__ zin,
    const float* __restrict__ W1, const float* __restrict__ b1,
    const float* __restrict__ g1, const float* __restrict__ be1,
    float* __restrict__ v)
{
    __shared__ float hs[2][HID];
    __shared__ float red[2][2][2];
    const int j = threadIdx.x & 127;
    const int local_n = threadIdx.x >> 7;
    const int wavehalf = (threadIdx.x >> 6) & 1;
    float w[HID];
#pragma unroll
    for (int k = 0; k < HID; ++k) w[k] = W1[k * HID2 + j];
    const float bias = b1[j];
    const float g = g1[j];
    const float be = be1[j];

    for (int base = blockIdx.x * 2; base < N_NODES; base += gridDim.x * 2) {
        __syncthreads();
        if (threadIdx.x < 128) {
            int nn = threadIdx.x >> 6, c = threadIdx.x & 63;
            int idx = (base + nn) * HID + c;
            hs[nn][c] = agg[idx] + zin[idx];
        }
        __syncthreads();
        const int n = base + local_n;
        float u = bias;
#pragma unroll
        for (int k4 = 0; k4 < HID / 4; ++k4) {
            float4 hv = ((const float4*)hs[local_n])[k4];
            u = fmaf(hv.x, w[k4 * 4 + 0], u);
            u = fmaf(hv.y, w[k4 * 4 + 1], u);
            u = fmaf(hv.z, w[k4 * 4 + 2], u);
            u = fmaf(hv.w, w[k4 * 4 + 3], u);
        }
        float ps_ = u;
#pragma unroll
        for (int o = 1; o < 64; o <<= 1) ps_ += __shfl_xor(ps_, o, 64);
        if ((threadIdx.x & 63) == 0) red[local_n][0][wavehalf] = ps_;
        __syncthreads();
        const float mu = (red[local_n][0][0] + red[local_n][0][1]) * (1.f / 128.f);
        const float d = u - mu;
        float q = d * d;
#pragma unroll
        for (int o = 1; o < 64; o <<= 1) q += __shfl_xor(q, o, 64);
        if ((threadIdx.x & 63) == 0) red[local_n][1][wavehalf] = q;
        __syncthreads();
        const float var = (red[local_n][1][0] + red[local_n][1][1]) * (1.f / 128.f);
        const float y = d * rsqrtf(var + 1e-5f) * g + be;
        v[n * HID2 + j] = y > 0.f ? y : 0.f;
    }
}

// ---------------------------------------------------------------------------
// mm2: out2 = v@W2 + b2 ; h = (residual? h:0) + out2 ;
//      z = relu(LN64(h)*gz+bz) ; zh = fp16(z)
// ---------------------------------------------------------------------------
__global__ __launch_bounds__(256, 2) void node_mm2_kernel(
    const float* __restrict__ v,
    const float* __restrict__ W2, const float* __restrict__ b2,
    const float* __restrict__ lng, const float* __restrict__ lnb,
    float* __restrict__ h, float* __restrict__ z, __half* __restrict__ zh,
    int residual)
{
    __shared__ float vs[4][HID2];
    const int c = threadIdx.x & 63;
    const int local_n = threadIdx.x >> 6;
    float w[HID2];
#pragma unroll
    for (int k = 0; k < HID2; ++k) w[k] = W2[k * HID + c];
    const float bias = b2[c];
    const float g = lng[c];
    const float be = lnb[c];

    for (int base = blockIdx.x * 4; base < N_NODES; base += gridDim.x * 4) {
        __syncthreads();
#pragma unroll
        for (int i = 0; i < 2; ++i) {
            int idx = threadIdx.x + i * 256;
            int nn = idx >> 7, kk = idx & 127;
            vs[nn][kk] = v[(base + nn) * HID2 + kk];
        }
        __syncthreads();
        const int n = base + local_n;
        float acc = bias;
#pragma unroll
        for (int k4 = 0; k4 < HID2 / 4; ++k4) {
            float4 vv = ((const float4*)vs[local_n])[k4];
            acc = fmaf(vv.x, w[k4 * 4 + 0], acc);
            acc = fmaf(vv.y, w[k4 * 4 + 1], acc);
            acc = fmaf(vv.z, w[k4 * 4 + 2], acc);
            acc = fmaf(vv.w, w[k4 * 4 + 3], acc);
        }
        const float hn = residual ? (h[n * HID + c] + acc) : acc;
        h[n * HID + c] = hn;
        float ps_ = hn;
#pragma unroll
        for (int o = 1; o < 64; o <<= 1) ps_ += __shfl_xor(ps_, o, 64);
        const float mu = ps_ * (1.f / 64.f);
        const float d = hn - mu;
        float q = d * d;
#pragma unroll
        for (int o = 1; o < 64; o <<= 1) q += __shfl_xor(q, o, 64);
        const float var = q * (1.f / 64.f);
        const float y = d * rsqrtf(var + 1e-5f) * g + be;
        const float zr = y > 0.f ? y : 0.f;
        z[n * HID + c] = zr;
        zh[n * HID + c] = __float2half(zr);
    }
}

// ---------------------------------------------------------------------------
// out = z @ lin_W + lin_b      [N,64]@[64,8]
// ---------------------------------------------------------------------------
__global__ __launch_bounds__(256, 4) void final_kernel(
    const float* __restrict__ z, const float* __restrict__ Wl,
    const float* __restrict__ bl, float* __restrict__ out)
{
    __shared__ float wl[HID * OUT_DIM];
    for (int i = threadIdx.x; i < HID * OUT_DIM; i += 256) wl[i] = Wl[i];
    __syncthreads();
    const int total = N_NODES * OUT_DIM;
    for (int idx = blockIdx.x * 256 + threadIdx.x; idx < total;
         idx += gridDim.x * 256) {
        const int n = idx >> 3, o = idx & 7;
        const float4* zp4 = (const float4*)(z + n * HID);
        float acc = bl[o];
#pragma unroll
        for (int k4 = 0; k4 < HID / 4; ++k4) {
            float4 zv = zp4[k4];
            acc = fmaf(zv.x, wl[(k4 * 4 + 0) * OUT_DIM + o], acc);
            acc = fmaf(zv.y, wl[(k4 * 4 + 1) * OUT_DIM + o], acc);
            acc = fmaf(zv.z, wl[(k4 * 4 + 2) * OUT_DIM + o], acc);
            acc = fmaf(zv.w, wl[(k4 * 4 + 3) * OUT_DIM + o], acc);
        }
        out[idx] = acc;
    }
}

// ---------------------------------------------------------------------------
extern "C" void kernel_launch(void* const* d_in, const int* in_sizes, int n_in,
                              void* d_out, int out_size, void* d_ws, size_t ws_size,
                              hipStream_t stream)
{
    const float* x         = (const float*)d_in[0];
    const float* edge_attr = (const float*)d_in[1];
    const float* node_W    = (const float*)d_in[2];
    const float* node_b    = (const float*)d_in[3];
    const float* edge_W    = (const float*)d_in[4];
    const float* edge_b    = (const float*)d_in[5];
    const float* conv_t    = (const float*)d_in[6];
    const float* conv_W1   = (const float*)d_in[7];
    const float* conv_b1   = (const float*)d_in[8];
    const float* conv_g1   = (const float*)d_in[9];
    const float* conv_be1  = (const float*)d_in[10];
    const float* conv_W2   = (const float*)d_in[11];
    const float* conv_b2   = (const float*)d_in[12];
    const float* ln_g      = (const float*)d_in[13];
    const float* ln_b      = (const float*)d_in[14];
    const float* lin_W     = (const float*)d_in[15];
    const float* lin_b     = (const float*)d_in[16];
    const int*   edge_index= (const int*)d_in[17];
    const int*   srcs = edge_index;
    const int*   dsts = edge_index + N_EDGES;
    float* out = (float*)d_out;

    // workspace layout (~180 MB)
    float* h   = (float*)d_ws;                    // N*64
    float* z   = h   + N_NODES * HID;             // N*64
    float* agg = z   + N_NODES * HID;             // N*64
    float* v   = agg + N_NODES * HID;             // N*128
    __half* zh  = (__half*)(v + N_NODES * HID2);  // N*64 half
    __half* eah = zh + (size_t)N_NODES * HID;     // E*64 half
    int* deg     = (int*)(eah + (size_t)N_EDGES * HID); // N
    int* offsets = deg + N_NODES;                 // N+1
    int* cursor  = offsets + N_NODES + 1;         // N
    int* inv     = cursor + N_NODES;              // E
    int* ssrc    = inv + N_EDGES;                 // E

    // ---- counting sort of edges by dst (once per call) ----
    hipMemsetAsync(deg, 0, (size_t)N_NODES * sizeof(int), stream);
    hist_kernel<<<1024, 256, 0, stream>>>(dsts, deg);
    scan_kernel<<<1, 1024, 0, stream>>>(deg, offsets);
    hipMemcpyAsync(cursor, offsets, (size_t)N_NODES * sizeof(int),
                   hipMemcpyDeviceToDevice, stream);
    scatter_kernel<<<1024, 256, 0, stream>>>(srcs, dsts, cursor, inv, ssrc);

    node_proj_kernel<<<2048, 256, 0, stream>>>(x, node_W, node_b, h, zh);
    edge_emb_kernel<<<3125, 256, 0, stream>>>(edge_attr, edge_W, edge_b, inv, eah);

    for (int layer = 0; layer < N_LAYERS; ++layer) {
        const float* zin = (layer == 0) ? h : z;
        edge_agg_kernel<<<12500, 256, 0, stream>>>(zh, eah, ssrc, offsets,
                                                   conv_t, layer, agg);
        node_mm1_kernel<<<2048, 256, 0, stream>>>(
            agg, zin,
            conv_W1 + (size_t)layer * HID * HID2, conv_b1 + layer * HID2,
            conv_g1 + layer * HID2, conv_be1 + layer * HID2, v);
        const float* gz = (layer < N_LAYERS - 1) ? (ln_g + (layer + 1) * HID) : ln_g;
        const float* bz = (layer < N_LAYERS - 1) ? (ln_b + (layer + 1) * HID) : ln_b;
        node_mm2_kernel<<<2048, 256, 0, stream>>>(
            v, conv_W2 + (size_t)layer * HID2 * HID, conv_b2 + layer * HID,
            gz, bz, h, z, zh, layer > 0 ? 1 : 0);
    }
    final_kernel<<<1024, 256, 0, stream>>>(z, lin_W, lin_b, out);
}